// Round 2
// baseline (346.874 us; speedup 1.0000x reference)
//
#include <hip/hip_runtime.h>
#include <math.h>

// Problem constants: B=4, H=W=64, C=128, NH=4, HD=32, K=7
#define TOK 16384
#define CH 128

// ---------------- LayerNorm: one wave per token, 2 ch/lane ----------------
__global__ __launch_bounds__(256) void ln_kernel(const float* __restrict__ x,
    const float* __restrict__ g, const float* __restrict__ b,
    float* __restrict__ y)
{
    int tok = blockIdx.x * 4 + (threadIdx.x >> 6);
    int lane = threadIdx.x & 63;
    float2 v = ((const float2*)(x + tok * CH))[lane];
    float s = v.x + v.y;
#pragma unroll
    for (int m = 32; m >= 1; m >>= 1) s += __shfl_xor(s, m);
    float mean = s * (1.0f / CH);
    float dx = v.x - mean, dy = v.y - mean;
    float vs = dx * dx + dy * dy;
#pragma unroll
    for (int m = 32; m >= 1; m >>= 1) vs += __shfl_xor(vs, m);
    float rs = rsqrtf(vs * (1.0f / CH) + 1e-5f);
    float2 gg = ((const float2*)g)[lane];
    float2 bb = ((const float2*)b)[lane];
    float2 o;
    o.x = dx * rs * gg.x + bb.x;
    o.y = dy * rs * gg.y + bb.y;
    ((float2*)(y + tok * CH))[lane] = o;
}

// ---------------- Generic fp32 GEMM, 64x64 tile, BK=16, 4x4/thread --------
// MODE 0: out = (A@W + bias) * scale
// MODE 1: out = A@W + bias + res
// MODE 2: out = gelu_exact(A@W + bias)
template<int MODE>
__global__ __launch_bounds__(256) void gemm64(const float* __restrict__ A,
    const float* __restrict__ W, const float* __restrict__ bias,
    const float* __restrict__ res, float* __restrict__ out,
    int N, int Kd, float scale)
{
    __shared__ float As[16][68];
    __shared__ float Bs[16][68];
    const int tid = threadIdx.x;
    const int m0 = blockIdx.x * 64, n0 = blockIdx.y * 64;
    const int tm = (tid >> 4) * 4;
    const int tn = (tid & 15) * 4;
    const int arow = tid >> 2, acol = (tid & 3) * 4;
    const int brow = tid >> 4, bcol = (tid & 15) * 4;
    const float* Ap = A + (size_t)(m0 + arow) * Kd + acol;
    const float* Wp = W + (size_t)brow * N + n0 + bcol;
    float acc[4][4] = {};
    for (int k0 = 0; k0 < Kd; k0 += 16) {
        float4 av = *(const float4*)(Ap + k0);
        float4 bv = *(const float4*)(Wp + (size_t)k0 * N);
        __syncthreads();
        As[acol + 0][arow] = av.x;
        As[acol + 1][arow] = av.y;
        As[acol + 2][arow] = av.z;
        As[acol + 3][arow] = av.w;
        *(float4*)&Bs[brow][bcol] = bv;
        __syncthreads();
#pragma unroll
        for (int kk = 0; kk < 16; ++kk) {
            float a[4], bb[4];
            *(float4*)a = *(const float4*)&As[kk][tm];
            *(float4*)bb = *(const float4*)&Bs[kk][tn];
#pragma unroll
            for (int ii = 0; ii < 4; ++ii)
#pragma unroll
                for (int jj = 0; jj < 4; ++jj)
                    acc[ii][jj] = fmaf(a[ii], bb[jj], acc[ii][jj]);
        }
    }
#pragma unroll
    for (int ii = 0; ii < 4; ++ii) {
        int row = m0 + tm + ii;
#pragma unroll
        for (int jj = 0; jj < 4; ++jj) {
            int col = n0 + tn + jj;
            float v = acc[ii][jj] + bias[col];
            if (MODE == 0) v *= scale;
            if (MODE == 1) v += res[(size_t)row * N + col];
            if (MODE == 2) v = 0.5f * v * (1.0f + erff(v * 0.70710678118654752f));
            out[(size_t)row * N + col] = v;
        }
    }
}

// ---------------- Neighborhood attention: one wave per (token, head) ------
// q: [TOK,128]; kv: [TOK,256] (k = ch 0..127, v = ch 128..255); rpb: [4,13,13]
__global__ __launch_bounds__(256) void nat_attn(const float* __restrict__ q,
    const float* __restrict__ kv, const float* __restrict__ rpb,
    float* __restrict__ out)
{
    __shared__ float sc[4][64];
    const int wid = threadIdx.x >> 6;
    const int lane = threadIdx.x & 63;
    const int job = blockIdx.x * 4 + wid;   // 65536 jobs = TOK * NH
    const int h = job & 3;
    const int t = job >> 2;
    const int j = t & 63;
    const int i = (t >> 6) & 63;
    const int b = t >> 12;
    const int si = min(max(i - 3, 0), 57);
    const int sj = min(max(j - 3, 0), 57);
    const int ld = lane & 31;
    const int half = lane >> 5;
    const int base_b = b << 12;
    const float qv = q[t * 128 + h * 32 + ld];

    // scores: two neighbors per wave (one per 32-lane half)
    for (int tt = 0; tt < 25; ++tt) {
        int n = tt * 2 + half;
        float partial = 0.0f;
        if (n < 49) {
            int r = si + n / 7, c = sj + n % 7;
            int t2 = base_b + r * 64 + c;
            partial = qv * kv[t2 * 256 + h * 32 + ld];
        }
        partial += __shfl_xor(partial, 16);
        partial += __shfl_xor(partial, 8);
        partial += __shfl_xor(partial, 4);
        partial += __shfl_xor(partial, 2);
        partial += __shfl_xor(partial, 1);
        if (ld == 0 && n < 49) sc[wid][n] = partial;
    }
    __syncthreads();
    // softmax over 49 (one score per lane) with rpb bias
    float s = -INFINITY;
    if (lane < 49) {
        int ri = si + lane / 7 - i + 6;
        int rj = sj + lane % 7 - j + 6;
        s = sc[wid][lane] + rpb[(h * 13 + ri) * 13 + rj];
    }
    float mx = s;
#pragma unroll
    for (int m = 32; m >= 1; m >>= 1) mx = fmaxf(mx, __shfl_xor(mx, m));
    float e = (lane < 49) ? expf(s - mx) : 0.0f;
    float sum = e;
#pragma unroll
    for (int m = 32; m >= 1; m >>= 1) sum += __shfl_xor(sum, m);
    float p = e / sum;
    __syncthreads();
    sc[wid][lane] = p;
    __syncthreads();
    // out[d] = sum_n p_n * v_n[d]; even n in half 0, odd n in half 1
    float acc = 0.0f;
    for (int tt = 0; tt < 25; ++tt) {
        int n = tt * 2 + half;
        if (n < 49) {
            int r = si + n / 7, c = sj + n % 7;
            int t2 = base_b + r * 64 + c;
            acc += sc[wid][n] * kv[t2 * 256 + 128 + h * 32 + ld];
        }
    }
    acc += __shfl_xor(acc, 32);
    if (half == 0) out[t * 128 + h * 32 + ld] = acc;
}

extern "C" void kernel_launch(void* const* d_in, const int* in_sizes, int n_in,
                              void* d_out, int out_size, void* d_ws, size_t ws_size,
                              hipStream_t stream) {
    const float* query     = (const float*)d_in[0];
    const float* key_value = (const float*)d_in[1];
    const float* g1 = (const float*)d_in[2];
    const float* b1 = (const float*)d_in[3];
    const float* g2 = (const float*)d_in[4];
    const float* b2 = (const float*)d_in[5];
    const float* g3 = (const float*)d_in[6];
    const float* b3 = (const float*)d_in[7];
    const float* Wq  = (const float*)d_in[8];
    const float* bq  = (const float*)d_in[9];
    const float* Wkv = (const float*)d_in[10];
    const float* bkv = (const float*)d_in[11];
    const float* Wp  = (const float*)d_in[12];
    const float* bp  = (const float*)d_in[13];
    const float* rpb = (const float*)d_in[14];
    const float* W1  = (const float*)d_in[15];
    const float* bm1 = (const float*)d_in[16];
    const float* W2  = (const float*)d_in[17];
    const float* bm2 = (const float*)d_in[18];

    float* ws = (float*)d_ws;
    // workspace layout (floats), with reuse; total 14,680,064 floats = 56 MB
    float* qn   = ws;              // 2M  (reused as attn_out)
    float* kvn  = ws + 2097152;    // 2M  (reused as x)
    float* qb   = ws + 4194304;    // 2M  (reused as xn)
    float* kvb  = ws + 6291456;    // 4M  (reused as h1: 8M)
    float* attn = ws;
    float* xb   = ws + 2097152;
    float* xn   = ws + 4194304;
    float* h1   = ws + 6291456;

    const float qscale = 0.17677669529663687f;  // HD^-0.5, HD=32

    ln_kernel<<<TOK / 4, 256, 0, stream>>>(query, g1, b1, qn);
    ln_kernel<<<TOK / 4, 256, 0, stream>>>(key_value, g2, b2, kvn);
    gemm64<0><<<dim3(TOK / 64, 2), 256, 0, stream>>>(qn,  Wq,  bq,  nullptr,   qb,  128, 128, qscale);
    gemm64<0><<<dim3(TOK / 64, 4), 256, 0, stream>>>(kvn, Wkv, bkv, nullptr,   kvb, 256, 128, 1.0f);
    nat_attn<<<TOK, 256, 0, stream>>>(qb, kvb, rpb, attn);   // 16384 blocks x 4 waves = 65536 jobs
    gemm64<1><<<dim3(TOK / 64, 2), 256, 0, stream>>>(attn, Wp, bp, key_value, xb,  128, 128, 1.0f);
    ln_kernel<<<TOK / 4, 256, 0, stream>>>(xb, g3, b3, xn);
    gemm64<2><<<dim3(TOK / 64, 8), 256, 0, stream>>>(xn,  W1, bm1, nullptr,   h1,  512, 128, 1.0f);
    gemm64<1><<<dim3(TOK / 64, 2), 256, 0, stream>>>(h1,  W2, bm2, xb, (float*)d_out, 128, 512, 1.0f);
}

// Round 3
// 210.676 us; speedup vs baseline: 1.6465x; 1.6465x over previous
//
#include <hip/hip_runtime.h>
#include <math.h>

// B=4, H=W=64, C=128, NH=4, HD=32, K=7, TOK=16384
#define TOK 16384

typedef __attribute__((ext_vector_type(8))) __bf16 bf16x8;
typedef __attribute__((ext_vector_type(4))) float f32x4;

__device__ inline unsigned short f2bf(float f) {
    union { float f; unsigned int u; } v; v.f = f;
    unsigned int r = v.u + 0x7fffu + ((v.u >> 16) & 1u);
    return (unsigned short)(r >> 16);
}

// ---------------- LayerNorm body: one wave per token, 2 ch/lane, bf16 out ----
__device__ inline void ln_body(const float* __restrict__ x, const float* __restrict__ g,
                               const float* __restrict__ b, unsigned short* __restrict__ y,
                               int tok, int lane)
{
    float2 v = ((const float2*)(x + (size_t)tok * 128))[lane];
    float s = v.x + v.y;
#pragma unroll
    for (int m = 32; m >= 1; m >>= 1) s += __shfl_xor(s, m);
    float mean = s * (1.0f / 128.0f);
    float dx = v.x - mean, dy = v.y - mean;
    float vs = dx * dx + dy * dy;
#pragma unroll
    for (int m = 32; m >= 1; m >>= 1) vs += __shfl_xor(vs, m);
    float rs = rsqrtf(vs * (1.0f / 128.0f) + 1e-5f);
    float2 gg = ((const float2*)g)[lane];
    float2 bb = ((const float2*)b)[lane];
    float ox = dx * rs * gg.x + bb.x;
    float oy = dy * rs * gg.y + bb.y;
    unsigned int pk = (unsigned int)f2bf(ox) | ((unsigned int)f2bf(oy) << 16);
    ((unsigned int*)(y + (size_t)tok * 128))[lane] = pk;
}

// ---------------- prep: LN1 + LN2 + weight transpose/convert to bf16 --------
// blocks [0,4096): LN1(query->qnh)  [4096,8192): LN2(key_value->kvnh)
// blocks [8192,8960): transpose-convert 196608 weight elems into Wt (bf16 [N][K] -> stored [n][k])
__global__ __launch_bounds__(256) void prep_kernel(
    const float* __restrict__ query, const float* __restrict__ key_value,
    const float* __restrict__ g1, const float* __restrict__ b1,
    const float* __restrict__ g2, const float* __restrict__ b2,
    const float* __restrict__ Wq, const float* __restrict__ Wkv,
    const float* __restrict__ Wp, const float* __restrict__ W1, const float* __restrict__ W2,
    unsigned short* __restrict__ qnh, unsigned short* __restrict__ kvnh,
    unsigned short* __restrict__ Wt)
{
    int blk = blockIdx.x, tid = threadIdx.x;
    if (blk < 8192) {
        int lane = tid & 63;
        if (blk < 4096) ln_body(query,     g1, b1, qnh,  blk * 4 + (tid >> 6), lane);
        else            ln_body(key_value, g2, b2, kvnh, (blk - 4096) * 4 + (tid >> 6), lane);
        return;
    }
    int gid = (blk - 8192) * 256 + tid;   // [0, 196608)
    const float* src; int Kd, Nd, li;
    if      (gid < 16384)  { src = Wq;  Kd = 128; Nd = 128; li = gid; }
    else if (gid < 49152)  { src = Wkv; Kd = 128; Nd = 256; li = gid - 16384; }
    else if (gid < 65536)  { src = Wp;  Kd = 128; Nd = 128; li = gid - 49152; }
    else if (gid < 131072) { src = W1;  Kd = 128; Nd = 512; li = gid - 65536; }
    else                   { src = W2;  Kd = 512; Nd = 128; li = gid - 131072; }
    int n = li / Kd, k = li % Kd;                 // Kd is pow2
    Wt[gid] = f2bf(src[(size_t)k * Nd + n]);
}

// ---------------- standalone LN (LN3), bf16 out -----------------------------
__global__ __launch_bounds__(256) void ln3_kernel(const float* __restrict__ x,
    const float* __restrict__ g, const float* __restrict__ b, unsigned short* __restrict__ y)
{
    ln_body(x, g, b, y, blockIdx.x * 4 + (threadIdx.x >> 6), threadIdx.x & 63);
}

// ---------------- bf16 MFMA GEMM: wave tile 32x64, no LDS, direct global ----
// out = A[M][K](bf16) @ Wt[N][K]^T(bf16) + bias, fp32 accumulate.
// MODE 0: outF = v*scale   MODE 1: outF = v + res   MODE 2: outH = bf16(gelu(v))
template<int MODE>
__global__ __launch_bounds__(256) void gemm_mfma(
    const unsigned short* __restrict__ A, const unsigned short* __restrict__ Wt,
    const float* __restrict__ bias, const float* __restrict__ res,
    float* __restrict__ outF, unsigned short* __restrict__ outH,
    int M, int N, int K, float scale)
{
    const int wave = threadIdx.x >> 6, lane = threadIdx.x & 63;
    const int wm = wave & 1, wn = wave >> 1;
    const int m0 = blockIdx.x * 64 + wm * 32;
    const int n0 = blockIdx.y * 128 + wn * 64;
    const int lr = lane & 15;      // row (A) / col (B) within frag
    const int lg = lane >> 4;      // k-group (8 elems each)
    f32x4 acc[2][4] = {};
#pragma unroll 4
    for (int k0 = 0; k0 < K; k0 += 32) {
        bf16x8 a[2], b[4];
#pragma unroll
        for (int mf = 0; mf < 2; ++mf)
            a[mf] = *(const bf16x8*)(A + (size_t)(m0 + mf * 16 + lr) * K + k0 + lg * 8);
#pragma unroll
        for (int nf = 0; nf < 4; ++nf)
            b[nf] = *(const bf16x8*)(Wt + (size_t)(n0 + nf * 16 + lr) * K + k0 + lg * 8);
#pragma unroll
        for (int mf = 0; mf < 2; ++mf)
#pragma unroll
            for (int nf = 0; nf < 4; ++nf)
                acc[mf][nf] = __builtin_amdgcn_mfma_f32_16x16x32_bf16(a[mf], b[nf], acc[mf][nf], 0, 0, 0);
    }
    // C/D layout (m89): col = lane&15, row = (lane>>4)*4 + reg
#pragma unroll
    for (int nf = 0; nf < 4; ++nf) {
        int gc = n0 + nf * 16 + lr;
        float bs = bias[gc];
#pragma unroll
        for (int mf = 0; mf < 2; ++mf) {
            int gr0 = m0 + mf * 16 + lg * 4;
#pragma unroll
            for (int r = 0; r < 4; ++r) {
                float v = acc[mf][nf][r] + bs;
                size_t idx = (size_t)(gr0 + r) * N + gc;
                if (MODE == 0) outF[idx] = v * scale;
                if (MODE == 1) outF[idx] = v + res[idx];
                if (MODE == 2) {
                    float gl = 0.5f * v * (1.0f + erff(v * 0.70710678118654752f));
                    outH[idx] = f2bf(gl);
                }
            }
        }
    }
}

// ---------------- Neighborhood attention, LDS-tiled -------------------------
// Block = (b, head, 8x8 query tile). 256 thr = 64 queries x 4 dim-groups(8 dims).
// LDS: halo K (then V, reused) 196 x 36(f32), scores 64 x 52.
__global__ __launch_bounds__(256) void nat_attn(const float* __restrict__ q,
    const float* __restrict__ kv, const float* __restrict__ rpb,
    unsigned short* __restrict__ out)
{
    __shared__ float Ks[196 * 36];
    __shared__ float Sc[64 * 52];
    const int tid = threadIdx.x;
    const int bid = blockIdx.x;
    const int tile = bid & 63, h = (bid >> 6) & 3, b = bid >> 8;
    const int ti0 = (tile >> 3) * 8, tj0 = (tile & 7) * 8;
    const int hr0 = min(max(ti0 - 3, 0), 50);
    const int hc0 = min(max(tj0 - 3, 0), 50);
    const int bb = b << 12;

    // ---- stage K halo (196 pos x 32 ch) ----
    for (int u = tid; u < 1568; u += 256) {
        int pos = u >> 3, f = u & 7;
        int rr = pos / 14, cc = pos - rr * 14;
        int t2 = bb + (hr0 + rr) * 64 + (hc0 + cc);
        *(float4*)&Ks[pos * 36 + f * 4] = *(const float4*)(kv + (size_t)t2 * 256 + h * 32 + f * 4);
    }
    const int qi = tid >> 2, dg = tid & 3;
    const int gi = ti0 + (qi >> 3), gj = tj0 + (qi & 7);
    const int t = bb + gi * 64 + gj;
    const int si = min(max(gi - 3, 0), 57), sj = min(max(gj - 3, 0), 57);
    const int li0 = si - hr0, lj0 = sj - hc0;
    const float* qp = q + (size_t)t * 128 + h * 32 + dg * 8;
    float4 q0 = *(const float4*)qp;
    float4 q1 = *(const float4*)(qp + 4);
    __syncthreads();

    // ---- scores: 49 neighbors, partial dot over 8 dims, reduce over 4 dg lanes
    const int rbase = (h * 13 + (si - gi + 6)) * 13 + (sj - gj + 6);
    for (int rr = 0; rr < 7; ++rr) {
#pragma unroll
        for (int cc = 0; cc < 7; ++cc) {
            const float* kp = &Ks[((li0 + rr) * 14 + lj0 + cc) * 36 + dg * 8];
            float4 k0 = *(const float4*)kp;
            float4 k1 = *(const float4*)(kp + 4);
            float s = q0.x * k0.x + q0.y * k0.y + q0.z * k0.z + q0.w * k0.w
                    + q1.x * k1.x + q1.y * k1.y + q1.z * k1.z + q1.w * k1.w;
            s += __shfl_xor(s, 1);
            s += __shfl_xor(s, 2);
            if (dg == 0) Sc[qi * 52 + rr * 7 + cc] = s + rpb[rbase + rr * 13 + cc];
        }
    }
    __syncthreads();   // scores visible; all K reads done

    // ---- stage V into same LDS; overlap with softmax stats from Sc ----
    for (int u = tid; u < 1568; u += 256) {
        int pos = u >> 3, f = u & 7;
        int rr = pos / 14, cc = pos - rr * 14;
        int t2 = bb + (hr0 + rr) * 64 + (hc0 + cc);
        *(float4*)&Ks[pos * 36 + f * 4] = *(const float4*)(kv + (size_t)t2 * 256 + 128 + h * 32 + f * 4);
    }
    float mx = -INFINITY;
#pragma unroll 7
    for (int n = 0; n < 49; ++n) mx = fmaxf(mx, Sc[qi * 52 + n]);
    float sum = 0.0f;
#pragma unroll 7
    for (int n = 0; n < 49; ++n) sum += expf(Sc[qi * 52 + n] - mx);
    float rinv = 1.0f / sum;
    __syncthreads();   // V visible

    // ---- PV: acc over 49 neighbors, 8 dims/thread ----
    float a0 = 0, a1 = 0, a2 = 0, a3 = 0, a4 = 0, a5 = 0, a6 = 0, a7 = 0;
    for (int rr = 0; rr < 7; ++rr) {
#pragma unroll
        for (int cc = 0; cc < 7; ++cc) {
            float p = expf(Sc[qi * 52 + rr * 7 + cc] - mx) * rinv;
            const float* vp = &Ks[((li0 + rr) * 14 + lj0 + cc) * 36 + dg * 8];
            float4 v0 = *(const float4*)vp;
            float4 v1 = *(const float4*)(vp + 4);
            a0 += p * v0.x; a1 += p * v0.y; a2 += p * v0.z; a3 += p * v0.w;
            a4 += p * v1.x; a5 += p * v1.y; a6 += p * v1.z; a7 += p * v1.w;
        }
    }
    uint4 pk;
    pk.x = (unsigned int)f2bf(a0) | ((unsigned int)f2bf(a1) << 16);
    pk.y = (unsigned int)f2bf(a2) | ((unsigned int)f2bf(a3) << 16);
    pk.z = (unsigned int)f2bf(a4) | ((unsigned int)f2bf(a5) << 16);
    pk.w = (unsigned int)f2bf(a6) | ((unsigned int)f2bf(a7) << 16);
    *(uint4*)(out + (size_t)t * 128 + h * 32 + dg * 8) = pk;
}

extern "C" void kernel_launch(void* const* d_in, const int* in_sizes, int n_in,
                              void* d_out, int out_size, void* d_ws, size_t ws_size,
                              hipStream_t stream) {
    const float* query     = (const float*)d_in[0];
    const float* key_value = (const float*)d_in[1];
    const float* g1 = (const float*)d_in[2];
    const float* b1 = (const float*)d_in[3];
    const float* g2 = (const float*)d_in[4];
    const float* b2 = (const float*)d_in[5];
    const float* g3 = (const float*)d_in[6];
    const float* b3 = (const float*)d_in[7];
    const float* Wq  = (const float*)d_in[8];
    const float* bq  = (const float*)d_in[9];
    const float* Wkv = (const float*)d_in[10];
    const float* bkv = (const float*)d_in[11];
    const float* Wp  = (const float*)d_in[12];
    const float* bp  = (const float*)d_in[13];
    const float* rpb = (const float*)d_in[14];
    const float* W1  = (const float*)d_in[15];
    const float* bm1 = (const float*)d_in[16];
    const float* W2  = (const float*)d_in[17];
    const float* bm2 = (const float*)d_in[18];

    char* ws = (char*)d_ws;
    // byte layout (total 54.9 MB; round-2 verified ws >= 58.7 MB)
    float*          kvb  = (float*)(ws + 0);                  // 16 MB  f32 [TOK][256]
    float*          qb   = (float*)(ws + 16777216);           //  8 MB  f32 [TOK][128]
    float*          xb   = (float*)(ws + 25165824);           //  8 MB  f32 [TOK][128]
    unsigned short* bufD = (unsigned short*)(ws + 33554432);  //  4 MB  bf16: qnh -> attnh -> xnh
    unsigned short* kvnh = (unsigned short*)(ws + 37748736);  //  4 MB  bf16 (dead after gemmKV)
    unsigned short* h1h  = (unsigned short*)(ws + 37748736);  // 16 MB  bf16 (overlaps kvnh, later)
    unsigned short* Wt   = (unsigned short*)(ws + 54525952);  // 384 KB bf16 transposed weights
    unsigned short* WtQ  = Wt;
    unsigned short* WtKV = Wt + 16384;
    unsigned short* WtP  = Wt + 49152;
    unsigned short* WtW1 = Wt + 65536;
    unsigned short* WtW2 = Wt + 131072;

    const float qscale = 0.17677669529663687f;  // HD^-0.5

    prep_kernel<<<8960, 256, 0, stream>>>(query, key_value, g1, b1, g2, b2,
                                          Wq, Wkv, Wp, W1, W2, bufD, kvnh, Wt);
    gemm_mfma<0><<<dim3(TOK / 64, 1), 256, 0, stream>>>(bufD, WtQ,  bq,  nullptr,   qb,  nullptr, TOK, 128, 128, qscale);
    gemm_mfma<0><<<dim3(TOK / 64, 2), 256, 0, stream>>>(kvnh, WtKV, bkv, nullptr,   kvb, nullptr, TOK, 256, 128, 1.0f);
    nat_attn<<<1024, 256, 0, stream>>>(qb, kvb, rpb, bufD);
    gemm_mfma<1><<<dim3(TOK / 64, 1), 256, 0, stream>>>(bufD, WtP,  bp,  key_value, xb,  nullptr, TOK, 128, 128, 1.0f);
    ln3_kernel<<<4096, 256, 0, stream>>>(xb, g3, b3, bufD);
    gemm_mfma<2><<<dim3(TOK / 64, 4), 256, 0, stream>>>(bufD, WtW1, bm1, nullptr,   nullptr, h1h, TOK, 512, 128, 1.0f);
    gemm_mfma<1><<<dim3(TOK / 64, 1), 256, 0, stream>>>(h1h,  WtW2, bm2, xb, (float*)d_out, nullptr, TOK, 128, 512, 1.0f);
}